// Round 7
// baseline (341.087 us; speedup 1.0000x reference)
//
#include <hip/hip_runtime.h>
#include <hip/hip_bf16.h>
#include <cstddef>

// ---------------------------------------------------------------------------
// MultiHeadedAttention forward: x[4096,2048] -> out[4096,2048] (fp32)
//   qkv = x @ W_in^T  (bf16 MFMA; Q-scale folded into W_in rows<2048 at cvt)
//   vtrans: V -> vtg[head*128+feat][tok] (tok swizzled) for attn PV staging
//   flash attention, causal, NH=16, HD=128, max-free softmax (|S|<~3)
//   out = y @ W_out^T (bf16 MFMA, fp32 out)
// ---------------------------------------------------------------------------

typedef __attribute__((ext_vector_type(8))) short short8;
typedef __attribute__((ext_vector_type(4))) float f32x4;

#define MFMA16(a, b, c) __builtin_amdgcn_mfma_f32_16x16x32_bf16((a), (b), (c), 0, 0, 0)

#define GLOAD_LDS16(gptr, lptr)                                                          \
  __builtin_amdgcn_global_load_lds((const __attribute__((address_space(1))) void*)(gptr), \
                                   (__attribute__((address_space(3))) void*)(lptr), 16, 0, 0)

// Ps row swizzle: involution within a 64-col row; write lanes (vary q&7) get
// distinct bank groups, reads are row-uniform (broadcast-preserving).
#define PSWZ(q) ((((q) & 7) ^ ((q) >> 3)) << 3)

__device__ __forceinline__ short f2bf(float f) {
  __hip_bfloat16 h = __float2bfloat16(f);
  return *reinterpret_cast<short*>(&h);
}

__device__ __forceinline__ void storeC(float* p, float v) { *p = v; }
__device__ __forceinline__ void storeC(short* p, float v) { *p = f2bf(v); }

// ------------------------------------------- fp32->bf16 (first scaleN scaled)
__global__ void cvt_bf16(const float* __restrict__ in, short* __restrict__ out,
                         long n, float scale, long scaleN) {
  long i = ((long)blockIdx.x * 256 + threadIdx.x) * 8;
  if (i >= n) return;
  float s = (i < scaleN) ? scale : 1.0f;   // regions are 8-aligned
  f32x4 a = *(const f32x4*)(in + i);
  f32x4 b = *(const f32x4*)(in + i + 4);
  short8 o;
  o[0] = f2bf(a[0] * s); o[1] = f2bf(a[1] * s); o[2] = f2bf(a[2] * s); o[3] = f2bf(a[3] * s);
  o[4] = f2bf(b[0] * s); o[5] = f2bf(b[1] * s); o[6] = f2bf(b[2] * s); o[7] = f2bf(b[3] * s);
  *(short8*)(out + i) = o;
}

// ------------------------------------------------------- C = A * B^T (gemm_bt)
template <typename CT>
__global__ __launch_bounds__(256, 2)
void gemm_bt(const short* __restrict__ A, const short* __restrict__ B,
             CT* __restrict__ C, int M, int N, int K) {
  __shared__ short As[128 * 32];
  __shared__ short Bs[128 * 32];
  const int tid = threadIdx.x;
  const int wave = tid >> 6, lane = tid & 63;
  const int g = lane >> 4, fr = lane & 15;
  const int wr = (wave >> 1) * 64, wc = (wave & 1) * 64;
  const int bm = blockIdx.y * 128, bn = blockIdx.x * 128;

  f32x4 acc[4][4] = {};

  for (int k0 = 0; k0 < K; k0 += 32) {
    __syncthreads();
#pragma unroll
    for (int i = 0; i < 2; ++i) {
      int Ci = i * 256 + tid;
      int row = Ci >> 2, c = Ci & 3;
      int sc = c ^ (row & 3);
      GLOAD_LDS16(A + (size_t)(bm + row) * K + k0 + sc * 8, As + Ci * 8);
      GLOAD_LDS16(B + (size_t)(bn + row) * K + k0 + sc * 8, Bs + Ci * 8);
    }
    __syncthreads();

    short8 af[4], bfr[4];
#pragma unroll
    for (int m = 0; m < 4; ++m) {
      int row = wr + m * 16 + fr;
      int off = (g * 8) ^ ((row & 3) * 8);
      af[m] = *(const short8*)(As + row * 32 + off);
    }
#pragma unroll
    for (int n = 0; n < 4; ++n) {
      int row = wc + n * 16 + fr;
      int off = (g * 8) ^ ((row & 3) * 8);
      bfr[n] = *(const short8*)(Bs + row * 32 + off);
    }
#pragma unroll
    for (int m = 0; m < 4; ++m)
#pragma unroll
      for (int n = 0; n < 4; ++n)
        acc[m][n] = MFMA16(af[m], bfr[n], acc[m][n]);
  }

#pragma unroll
  for (int m = 0; m < 4; ++m) {
#pragma unroll
    for (int r = 0; r < 4; ++r) {
      size_t row = (size_t)(bm + wr + m * 16 + g * 4 + r);
      CT* cp = C + row * N + bn + wc + fr;
#pragma unroll
      for (int n = 0; n < 4; ++n)
        storeC(cp + n * 16, acc[m][n][r]);
    }
  }
}

// ----------------------------------------------------- V transpose + swizzle
__global__ __launch_bounds__(256, 4)
void vtrans(const short* __restrict__ qkv, short* __restrict__ vtg) {
  __shared__ short L[128 * 64];
  const int tid = threadIdx.x;
  const int tb = blockIdx.x * 64;   // token base
  const int h = blockIdx.y;
#pragma unroll
  for (int i = 0; i < 4; ++i) {
    int Ci = i * 256 + tid, tok = Ci >> 4, c = Ci & 15, f0 = c * 8;
    short8 v = *(const short8*)(qkv + (size_t)(tb + tok) * 6144 + 4096 + h * 128 + f0);
#pragma unroll
    for (int j = 0; j < 8; ++j) {
      int f = f0 + j;
      L[f * 64 + (tok ^ ((((f & 7) ^ ((f >> 3) & 7)) << 3)))] = v[j];
    }
  }
  __syncthreads();
  const int f = tid >> 1, half = (tid & 1) * 32;
  const int s_in = ((f & 7) ^ ((f >> 3) & 7)) << 3;
  const int s_out = (f & 7) << 3;
#pragma unroll
  for (int j2 = 0; j2 < 4; ++j2) {
    int t0 = half + j2 * 8;
    short8 v = *(const short8*)(&L[f * 64 + (t0 ^ s_in)]);
    *(short8*)(vtg + (size_t)(h * 128 + f) * 4096 + tb + (t0 ^ s_out)) = v;
  }
}

// -------------------------------------------------------------- attention
// Grid 256 blocks: 16 causal-balanced pairs x 16 heads (2 heads per XCD).
// Block = 4 waves x 32 q-rows; KVBLK=64; 66 tiles/block. LDS exactly 80 KB
// -> 2 blocks/CU (2 waves/SIMD: latency hiding restored vs R5).
__global__ __launch_bounds__(256, 2)
void attn_fwd(const short* __restrict__ qkv, const short* __restrict__ vtg,
              short* __restrict__ y) {
  __shared__ short Ks[2][64 * 128];   // 32 KB: K dbuf, chunk-swizzled (c^=key&7)
  __shared__ short Vt[2][128 * 64];   // 32 KB: V^T dbuf [feat][key^((feat&7)<<3)]
  __shared__ short Ps[4][32 * 64];    // 16 KB: per-wave P [q][key^PSWZ(q)]
  const int tid = threadIdx.x;
  const int wave = tid >> 6, lane = tid & 63;
  const int g = lane >> 4, fr = lane & 15;

  const int wgid = blockIdx.x;
  const int slot = wgid >> 3;
  const int h = ((wgid & 7) << 1) | (slot >> 4);  // 2 heads per XCD
  const int pair = slot & 15;

  short* Pw = Ps[wave];

  short8 onesf;
#pragma unroll
  for (int j = 0; j < 8; ++j) onesf[j] = (short)0x3F80;  // bf16 1.0

#pragma unroll 1
  for (int phase = 0; phase < 2; ++phase) {
    const int xb = phase ? (31 - pair) : pair;
    const int qw = xb * 128 + wave * 32;
    const int ntiles = 2 * xb + 2;

    short8 qf[2][4];
#pragma unroll
    for (int mi = 0; mi < 2; ++mi) {
      const short* Qp = qkv + (size_t)(qw + mi * 16 + fr) * 6144 + h * 128;
#pragma unroll
      for (int kk = 0; kk < 4; ++kk)
        qf[mi][kk] = *(const short8*)(Qp + kk * 32 + g * 8);
    }
    f32x4 oacc[2][8] = {};
    f32x4 lacc[2] = {};

    // prologue: stage K0 -> Ks[0], V0 -> Vt[0]
#pragma unroll
    for (int i = 0; i < 4; ++i) {
      int Ci = i * 256 + tid, key = Ci >> 4, c = Ci & 15, sc = c ^ (key & 7);
      GLOAD_LDS16(qkv + (size_t)key * 6144 + 2048 + h * 128 + sc * 8, &Ks[0][Ci * 8]);
    }
#pragma unroll
    for (int i = 0; i < 4; ++i) {
      int Ci = i * 256 + tid, feat = Ci >> 3, ko = (Ci & 7) * 8;
      GLOAD_LDS16(vtg + (size_t)(h * 128 + feat) * 4096 + ko, &Vt[0][Ci * 8]);
    }
    __syncthreads();

#pragma unroll 1
    for (int t = 0; t < ntiles; ++t) {
      const int kv0 = t * 64;
      const int cur = t & 1;

      // A: prefetch next K,V tiles (land by end-of-tile barrier)
      if (t + 1 < ntiles) {
#pragma unroll
        for (int i = 0; i < 4; ++i) {
          int Ci = i * 256 + tid, key = Ci >> 4, c = Ci & 15, sc = c ^ (key & 7);
          GLOAD_LDS16(qkv + (size_t)(kv0 + 64 + key) * 6144 + 2048 + h * 128 + sc * 8,
                      &Ks[cur ^ 1][Ci * 8]);
        }
#pragma unroll
        for (int i = 0; i < 4; ++i) {
          int Ci = i * 256 + tid, feat = Ci >> 3, ko = (Ci & 7) * 8;
          GLOAD_LDS16(vtg + (size_t)(h * 128 + feat) * 4096 + kv0 + 64 + ko,
                      &Vt[cur ^ 1][Ci * 8]);
        }
      }

      // B: S = Q K^T; each kfrag feeds both m-frags
      f32x4 s[2][4] = {};
      __builtin_amdgcn_s_setprio(1);
#pragma unroll
      for (int nf = 0; nf < 4; ++nf) {
        const int key = nf * 16 + fr;
#pragma unroll
        for (int kk = 0; kk < 4; ++kk) {
          int off = (kk * 32 + g * 8) ^ ((key & 7) * 8);
          short8 kfrag = *(const short8*)(&Ks[cur][key * 128 + off]);
          s[0][nf] = MFMA16(qf[0][kk], kfrag, s[0][nf]);
          s[1][nf] = MFMA16(qf[1][kk], kfrag, s[1][nf]);
        }
      }
      __builtin_amdgcn_s_setprio(0);

      // C: P = exp2(S) (max-free); mask the last TWO tiles (diagonal region)
      if (t >= ntiles - 2) {
#pragma unroll
        for (int mi = 0; mi < 2; ++mi)
#pragma unroll
          for (int nf = 0; nf < 4; ++nf) {
            const int keyg = kv0 + nf * 16 + fr;
#pragma unroll
            for (int r = 0; r < 4; ++r) {
              const int q2 = mi * 16 + g * 4 + r;
              float p = (keyg <= qw + q2) ? __builtin_amdgcn_exp2f(s[mi][nf][r]) : 0.f;
              Pw[q2 * 64 + ((nf * 16 + fr) ^ PSWZ(q2))] = f2bf(p);
            }
          }
      } else {
#pragma unroll
        for (int mi = 0; mi < 2; ++mi)
#pragma unroll
          for (int nf = 0; nf < 4; ++nf)
#pragma unroll
            for (int r = 0; r < 4; ++r) {
              const int q2 = mi * 16 + g * 4 + r;
              Pw[q2 * 64 + ((nf * 16 + fr) ^ PSWZ(q2))] =
                  f2bf(__builtin_amdgcn_exp2f(s[mi][nf][r]));
            }
      }

      // D: O += P V ; l += P 1  (Pw wave-private; vf feeds both m-frags)
      __builtin_amdgcn_s_setprio(1);
#pragma unroll
      for (int kk = 0; kk < 2; ++kk) {
        const int rb = kk * 32 + g * 8;
        short8 pf0 = *(const short8*)(&Pw[fr * 64 + (rb ^ PSWZ(fr))]);
        short8 pf1 = *(const short8*)(&Pw[(16 + fr) * 64 + (rb ^ PSWZ(16 + fr))]);
        lacc[0] = MFMA16(pf0, onesf, lacc[0]);
        lacc[1] = MFMA16(pf1, onesf, lacc[1]);
#pragma unroll
        for (int nf = 0; nf < 8; ++nf) {
          int f = nf * 16 + fr;
          short8 vf = *(const short8*)(&Vt[cur][f * 64 + (rb ^ ((f & 7) * 8))]);
          oacc[0][nf] = MFMA16(pf0, vf, oacc[0][nf]);
          oacc[1][nf] = MFMA16(pf1, vf, oacc[1][nf]);
        }
      }
      __builtin_amdgcn_s_setprio(0);

      // E: all waves done with cur buffers; next stages landed (vmcnt drain)
      __syncthreads();
    }

    // epilogue: y = O / l
#pragma unroll
    for (int mi = 0; mi < 2; ++mi)
#pragma unroll
      for (int r = 0; r < 4; ++r) {
        float inv = 1.0f / lacc[mi][r];
        size_t row = (size_t)(qw + mi * 16 + g * 4 + r);
#pragma unroll
        for (int nf = 0; nf < 8; ++nf)
          y[row * 2048 + h * 128 + nf * 16 + fr] = f2bf(oacc[mi][nf][r] * inv);
      }
  }
}

// ---------------------------------------------------------------------------
extern "C" void kernel_launch(void* const* d_in, const int* in_sizes, int n_in,
                              void* d_out, int out_size, void* d_ws, size_t ws_size,
                              hipStream_t stream) {
  const float* x    = (const float*)d_in[0];   // [4096,2048]
  const float* Win  = (const float*)d_in[1];   // [6144,2048]
  const float* Wout = (const float*)d_in[2];   // [2048,2048]
  float* out = (float*)d_out;                  // [4096,2048] fp32

  char* ws = (char*)d_ws;
  // lifetimes: xb,Winb dead after GEMM1 -> yb aliases xb, vtg aliases Winb
  short* xb    = (short*)(ws);                 // 16 MB : x bf16       [0,16M)
  short* yb    = (short*)(ws);                 // 16 MB : y bf16       [0,16M)
  short* Winb  = (short*)(ws + 16777216);      // 24 MB : W_in bf16    [16M,40M)
  short* vtg   = (short*)(ws + 16777216);      // 16 MB : V^T swz      [16M,32M)
  short* Woutb = (short*)(ws + 41943040);      //  8 MB : W_out bf16   [40M,48M)
  short* qkv   = (short*)(ws + 50331648);      // 48 MB : qkv bf16     [48M,96M)

  // Q-scale folded into W_in rows [0,2048) = first 2048*2048 elements
  const float qscale = 0.08838834764831845f * 1.4426950408889634f;

  cvt_bf16<<<4096, 256, 0, stream>>>(x, xb, 8388608L, 1.0f, 0L);
  cvt_bf16<<<6144, 256, 0, stream>>>(Win, Winb, 12582912L, qscale, 4194304L);
  cvt_bf16<<<2048, 256, 0, stream>>>(Wout, Woutb, 4194304L, 1.0f, 0L);

  gemm_bt<short><<<dim3(48, 32), 256, 0, stream>>>(xb, Winb, qkv, 4096, 6144, 2048);

  vtrans<<<dim3(64, 16), 256, 0, stream>>>(qkv, vtg);

  attn_fwd<<<256, 256, 0, stream>>>(qkv, vtg, yb);

  gemm_bt<float><<<dim3(16, 32), 256, 0, stream>>>(yb, Woutb, out, 4096, 2048, 2048);
}

// Round 8
// 292.196 us; speedup vs baseline: 1.1673x; 1.1673x over previous
//
#include <hip/hip_runtime.h>
#include <hip/hip_bf16.h>
#include <cstddef>

// ---------------------------------------------------------------------------
// MultiHeadedAttention forward: x[4096,2048] -> out[4096,2048] (fp32)
//   qkv = x @ W_in^T  (bf16 MFMA, BK=64; Q-scale folded into W_in cvt)
//   vtrans: V -> vtg[head*128+feat][tok] (tok swizzled) for attn PV staging
//   flash attention, causal, NH=16, HD=128, max-free softmax (|S|<~3)
//   out = y @ W_out^T (bf16 MFMA, fp32 out)
// ---------------------------------------------------------------------------

typedef __attribute__((ext_vector_type(8))) short short8;
typedef __attribute__((ext_vector_type(4))) float f32x4;

#define MFMA16(a, b, c) __builtin_amdgcn_mfma_f32_16x16x32_bf16((a), (b), (c), 0, 0, 0)

#define GLOAD_LDS16(gptr, lptr)                                                          \
  __builtin_amdgcn_global_load_lds((const __attribute__((address_space(1))) void*)(gptr), \
                                   (__attribute__((address_space(3))) void*)(lptr), 16, 0, 0)

// Ps row swizzle (R6-verified): involution within a 64-col row; write lanes
// (vary q&7 via g) hit distinct bank groups; reads stay granule-aligned b128.
#define PSWZ(q) ((((q) & 7) ^ ((q) >> 3)) << 3)

__device__ __forceinline__ short f2bf(float f) {
  __hip_bfloat16 h = __float2bfloat16(f);
  return *reinterpret_cast<short*>(&h);
}

__device__ __forceinline__ void storeC(float* p, float v) { *p = v; }
__device__ __forceinline__ void storeC(short* p, float v) { *p = f2bf(v); }

// ------------------------------------------- fp32->bf16 (first scaleN scaled)
__global__ void cvt_bf16(const float* __restrict__ in, short* __restrict__ out,
                         long n, float scale, long scaleN) {
  long i = ((long)blockIdx.x * 256 + threadIdx.x) * 8;
  if (i >= n) return;
  float s = (i < scaleN) ? scale : 1.0f;   // regions are 8-aligned
  f32x4 a = *(const f32x4*)(in + i);
  f32x4 b = *(const f32x4*)(in + i + 4);
  short8 o;
  o[0] = f2bf(a[0] * s); o[1] = f2bf(a[1] * s); o[2] = f2bf(a[2] * s); o[3] = f2bf(a[3] * s);
  o[4] = f2bf(b[0] * s); o[5] = f2bf(b[1] * s); o[6] = f2bf(b[2] * s); o[7] = f2bf(b[3] * s);
  *(short8*)(out + i) = o;
}

// ------------------------------------------------------- C = A * B^T (gemm_bt)
// 128x128 tile, BK=64 (half the barrier-drain stalls of BK=32), 4 waves.
// Staging: 8 granules/row, source pre-swizzled sc = c ^ (row&7); fragment
// reads un-swizzle with off = (kk*32 + g*8) ^ ((row&7)*8). Frags per-kk to
// keep VGPR <= 128.
template <typename CT>
__global__ __launch_bounds__(256, 4)
void gemm_bt(const short* __restrict__ A, const short* __restrict__ B,
             CT* __restrict__ C, int M, int N, int K) {
  __shared__ short As[128 * 64];
  __shared__ short Bs[128 * 64];
  const int tid = threadIdx.x;
  const int wave = tid >> 6, lane = tid & 63;
  const int g = lane >> 4, fr = lane & 15;
  const int wr = (wave >> 1) * 64, wc = (wave & 1) * 64;
  const int bm = blockIdx.y * 128, bn = blockIdx.x * 128;

  f32x4 acc[4][4] = {};

  for (int k0 = 0; k0 < K; k0 += 64) {
    __syncthreads();
#pragma unroll
    for (int i = 0; i < 4; ++i) {
      int Ci = i * 256 + tid;
      int row = Ci >> 3, c = Ci & 7;
      int sc = c ^ (row & 7);
      GLOAD_LDS16(A + (size_t)(bm + row) * K + k0 + sc * 8, As + Ci * 8);
      GLOAD_LDS16(B + (size_t)(bn + row) * K + k0 + sc * 8, Bs + Ci * 8);
    }
    __syncthreads();

#pragma unroll
    for (int kk = 0; kk < 2; ++kk) {
      short8 af[4], bfr[4];
#pragma unroll
      for (int m = 0; m < 4; ++m) {
        int row = wr + m * 16 + fr;
        int off = (kk * 32 + g * 8) ^ ((row & 7) * 8);
        af[m] = *(const short8*)(As + row * 64 + off);
      }
#pragma unroll
      for (int n = 0; n < 4; ++n) {
        int row = wc + n * 16 + fr;
        int off = (kk * 32 + g * 8) ^ ((row & 7) * 8);
        bfr[n] = *(const short8*)(Bs + row * 64 + off);
      }
#pragma unroll
      for (int m = 0; m < 4; ++m)
#pragma unroll
        for (int n = 0; n < 4; ++n)
          acc[m][n] = MFMA16(af[m], bfr[n], acc[m][n]);
    }
  }

#pragma unroll
  for (int m = 0; m < 4; ++m) {
#pragma unroll
    for (int r = 0; r < 4; ++r) {
      size_t row = (size_t)(bm + wr + m * 16 + g * 4 + r);
      CT* cp = C + row * N + bn + wc + fr;
#pragma unroll
      for (int n = 0; n < 4; ++n)
        storeC(cp + n * 16, acc[m][n][r]);
    }
  }
}

// ----------------------------------------------------- V transpose + swizzle
__global__ __launch_bounds__(256, 4)
void vtrans(const short* __restrict__ qkv, short* __restrict__ vtg) {
  __shared__ short L[128 * 64];
  const int tid = threadIdx.x;
  const int tb = blockIdx.x * 64;   // token base
  const int h = blockIdx.y;
#pragma unroll
  for (int i = 0; i < 4; ++i) {
    int Ci = i * 256 + tid, tok = Ci >> 4, c = Ci & 15, f0 = c * 8;
    short8 v = *(const short8*)(qkv + (size_t)(tb + tok) * 6144 + 4096 + h * 128 + f0);
#pragma unroll
    for (int j = 0; j < 8; ++j) {
      int f = f0 + j;
      L[f * 64 + (tok ^ ((((f & 7) ^ ((f >> 3) & 7)) << 3)))] = v[j];
    }
  }
  __syncthreads();
  const int f = tid >> 1, half = (tid & 1) * 32;
  const int s_in = ((f & 7) ^ ((f >> 3) & 7)) << 3;
  const int s_out = (f & 7) << 3;
#pragma unroll
  for (int j2 = 0; j2 < 4; ++j2) {
    int t0 = half + j2 * 8;
    short8 v = *(const short8*)(&L[f * 64 + (t0 ^ s_in)]);
    *(short8*)(vtg + (size_t)(h * 128 + f) * 4096 + tb + (t0 ^ s_out)) = v;
  }
}

// -------------------------------------------------------------- attention
// R4-proven geometry: 512 blocks (32 causal-balanced pairs x 16 heads, 2 heads
// per XCD), 4 waves x 16 q-rows, KVBLK=64, 65 tiles/block, one barrier/tile,
// K+V double-buffered via global_load_lds. LDS 72 KB -> 2 blocks/CU.
// New vs R4: Ps[16x64] with PSWZ involution (R4's pad-72 swizzle was a no-op
// on the write side: 2.66e7 conflict-cycles).
__global__ __launch_bounds__(256, 2)
void attn_fwd(const short* __restrict__ qkv, const short* __restrict__ vtg,
              short* __restrict__ y) {
  __shared__ short Ks[2][64 * 128];   // 32 KB: K dbuf, chunk-swizzled (c^=key&7)
  __shared__ short Vt[2][128 * 64];   // 32 KB: V^T dbuf [feat][key^((feat&7)<<3)]
  __shared__ short Ps[4][16 * 64];    //  8 KB: per-wave P [q][key^PSWZ(q)]
  const int tid = threadIdx.x;
  const int wave = tid >> 6, lane = tid & 63;
  const int g = lane >> 4, fr = lane & 15;

  const int wgid = blockIdx.x;
  const int slot = wgid >> 3;
  const int h = ((wgid & 7) << 1) | (slot >> 5);  // head: 2 per XCD
  const int pair = slot & 31;

  short* Pw = Ps[wave];

  short8 onesf;
#pragma unroll
  for (int j = 0; j < 8; ++j) onesf[j] = (short)0x3F80;  // bf16 1.0

#pragma unroll 1
  for (int phase = 0; phase < 2; ++phase) {
    const int xb = phase ? (63 - pair) : pair;
    const int qw = xb * 64 + wave * 16;
    const int ntiles = xb + 1;

    short8 qf[4];
    {
      const short* Qp = qkv + (size_t)(qw + fr) * 6144 + h * 128;
#pragma unroll
      for (int kk = 0; kk < 4; ++kk)
        qf[kk] = *(const short8*)(Qp + kk * 32 + g * 8);
    }
    f32x4 oacc[8] = {};
    f32x4 lacc = {};   // row sums, same C/D layout as oacc

    // prologue: stage K0 -> Ks[0], V0 -> Vt[0]
#pragma unroll
    for (int i = 0; i < 4; ++i) {
      int Ci = i * 256 + tid, key = Ci >> 4, c = Ci & 15, sc = c ^ (key & 7);
      GLOAD_LDS16(qkv + (size_t)key * 6144 + 2048 + h * 128 + sc * 8, &Ks[0][Ci * 8]);
    }
#pragma unroll
    for (int i = 0; i < 4; ++i) {
      int Ci = i * 256 + tid, feat = Ci >> 3, ko = (Ci & 7) * 8;
      GLOAD_LDS16(vtg + (size_t)(h * 128 + feat) * 4096 + ko, &Vt[0][Ci * 8]);
    }
    __syncthreads();  // drain prologue stages; fences prior-phase LDS reads

#pragma unroll 1
    for (int t = 0; t < ntiles; ++t) {
      const int kv0 = t * 64;
      const int cur = t & 1;

      // A: prefetch next K,V tiles (land by end-of-tile barrier)
      if (t + 1 < ntiles) {
#pragma unroll
        for (int i = 0; i < 4; ++i) {
          int Ci = i * 256 + tid, key = Ci >> 4, c = Ci & 15, sc = c ^ (key & 7);
          GLOAD_LDS16(qkv + (size_t)(kv0 + 64 + key) * 6144 + 2048 + h * 128 + sc * 8,
                      &Ks[cur ^ 1][Ci * 8]);
        }
#pragma unroll
        for (int i = 0; i < 4; ++i) {
          int Ci = i * 256 + tid, feat = Ci >> 3, ko = (Ci & 7) * 8;
          GLOAD_LDS16(vtg + (size_t)(h * 128 + feat) * 4096 + kv0 + 64 + ko,
                      &Vt[cur ^ 1][Ci * 8]);
        }
      }

      // B: S = Q K^T (lane: rows q = qw+g*4+r, col key = kv0+nf*16+fr)
      f32x4 s[4] = {};
      __builtin_amdgcn_s_setprio(1);
#pragma unroll
      for (int nf = 0; nf < 4; ++nf) {
        const int key = nf * 16 + fr;
#pragma unroll
        for (int kk = 0; kk < 4; ++kk) {
          int off = (kk * 32 + g * 8) ^ ((key & 7) * 8);
          short8 kfrag = *(const short8*)(&Ks[cur][key * 128 + off]);
          s[nf] = MFMA16(qf[kk], kfrag, s[nf]);
        }
      }
      __builtin_amdgcn_s_setprio(0);

      // C: P = exp2(S) (max-free), causal mask only on the diagonal tile
      if (t == ntiles - 1) {
#pragma unroll
        for (int nf = 0; nf < 4; ++nf) {
          const int keyg = kv0 + nf * 16 + fr;
#pragma unroll
          for (int r = 0; r < 4; ++r) {
            const int q = g * 4 + r;
            float p = (keyg <= qw + q) ? __builtin_amdgcn_exp2f(s[nf][r]) : 0.f;
            Pw[q * 64 + ((nf * 16 + fr) ^ PSWZ(q))] = f2bf(p);
          }
        }
      } else {
#pragma unroll
        for (int nf = 0; nf < 4; ++nf)
#pragma unroll
          for (int r = 0; r < 4; ++r) {
            const int q = g * 4 + r;
            Pw[q * 64 + ((nf * 16 + fr) ^ PSWZ(q))] =
                f2bf(__builtin_amdgcn_exp2f(s[nf][r]));
          }
      }

      // D: O += P V ; l += P 1  (Pw wave-private: no barrier before reads)
      __builtin_amdgcn_s_setprio(1);
#pragma unroll
      for (int kk = 0; kk < 2; ++kk) {
        const int rb = kk * 32 + g * 8;
        short8 pf = *(const short8*)(&Pw[fr * 64 + (rb ^ PSWZ(fr))]);
        lacc = MFMA16(pf, onesf, lacc);
#pragma unroll
        for (int nf = 0; nf < 8; ++nf) {
          int f = nf * 16 + fr;
          short8 vf = *(const short8*)(&Vt[cur][f * 64 + (rb ^ ((f & 7) * 8))]);
          oacc[nf] = MFMA16(pf, vf, oacc[nf]);
        }
      }
      __builtin_amdgcn_s_setprio(0);

      // E: all waves done with cur buffers; next stages landed (vmcnt drain)
      __syncthreads();
    }

    // epilogue: y = O / l
#pragma unroll
    for (int r = 0; r < 4; ++r) {
      float inv = 1.0f / lacc[r];
      size_t row = (size_t)(qw + g * 4 + r);
#pragma unroll
      for (int nf = 0; nf < 8; ++nf)
        y[row * 2048 + h * 128 + nf * 16 + fr] = f2bf(oacc[nf][r] * inv);
    }
  }
}

// ---------------------------------------------------------------------------
extern "C" void kernel_launch(void* const* d_in, const int* in_sizes, int n_in,
                              void* d_out, int out_size, void* d_ws, size_t ws_size,
                              hipStream_t stream) {
  const float* x    = (const float*)d_in[0];   // [4096,2048]
  const float* Win  = (const float*)d_in[1];   // [6144,2048]
  const float* Wout = (const float*)d_in[2];   // [2048,2048]
  float* out = (float*)d_out;                  // [4096,2048] fp32

  char* ws = (char*)d_ws;
  // lifetimes: xb,Winb dead after GEMM1 -> yb aliases xb, vtg aliases Winb
  short* xb    = (short*)(ws);                 // 16 MB : x bf16       [0,16M)
  short* yb    = (short*)(ws);                 // 16 MB : y bf16       [0,16M)
  short* Winb  = (short*)(ws + 16777216);      // 24 MB : W_in bf16    [16M,40M)
  short* vtg   = (short*)(ws + 16777216);      // 16 MB : V^T swz      [16M,32M)
  short* Woutb = (short*)(ws + 41943040);      //  8 MB : W_out bf16   [40M,48M)
  short* qkv   = (short*)(ws + 50331648);      // 48 MB : qkv bf16     [48M,96M)

  // Q-scale folded into W_in rows [0,2048) = first 2048*2048 elements
  const float qscale = 0.08838834764831845f * 1.4426950408889634f;

  cvt_bf16<<<4096, 256, 0, stream>>>(x, xb, 8388608L, 1.0f, 0L);
  cvt_bf16<<<6144, 256, 0, stream>>>(Win, Winb, 12582912L, qscale, 4194304L);
  cvt_bf16<<<2048, 256, 0, stream>>>(Wout, Woutb, 4194304L, 1.0f, 0L);

  gemm_bt<short><<<dim3(48, 32), 256, 0, stream>>>(xb, Winb, qkv, 4096, 6144, 2048);

  vtrans<<<dim3(64, 16), 256, 0, stream>>>(qkv, vtg);

  attn_fwd<<<512, 256, 0, stream>>>(qkv, vtg, yb);

  gemm_bt<float><<<dim3(16, 32), 256, 0, stream>>>(yb, Woutb, out, 4096, 2048, 2048);
}

// Round 9
// 284.203 us; speedup vs baseline: 1.2002x; 1.0281x over previous
//
#include <hip/hip_runtime.h>
#include <hip/hip_bf16.h>
#include <cstddef>

// ---------------------------------------------------------------------------
// MultiHeadedAttention forward: x[4096,2048] -> out[4096,2048] (fp32)
//   qkv = x @ W_in^T  (bf16 MFMA, BK=64; Q-scale folded into W_in cvt)
//   vtrans: V -> vtg[head*128+feat][tok] (tok swizzled) for attn PV staging
//   flash attention, causal, NH=16, HD=128, max-free softmax (|S|<~3)
//   out = y @ W_out^T (bf16 MFMA, fp32 out)
// ---------------------------------------------------------------------------

typedef __attribute__((ext_vector_type(8))) short short8;
typedef __attribute__((ext_vector_type(4))) float f32x4;

#define MFMA16(a, b, c) __builtin_amdgcn_mfma_f32_16x16x32_bf16((a), (b), (c), 0, 0, 0)

#define GLOAD_LDS16(gptr, lptr)                                                          \
  __builtin_amdgcn_global_load_lds((const __attribute__((address_space(1))) void*)(gptr), \
                                   (__attribute__((address_space(3))) void*)(lptr), 16, 0, 0)

// Ps row swizzle: involution within a 64-col row; write lanes (vary q&7 via g)
// spread bank groups (2-way = free); b128 reads stay granule-aligned.
#define PSWZ(q) ((((q) & 7) ^ ((q) >> 3)) << 3)

__device__ __forceinline__ short f2bf(float f) {
  __hip_bfloat16 h = __float2bfloat16(f);
  return *reinterpret_cast<short*>(&h);
}

__device__ __forceinline__ void storeC(float* p, float v) { *p = v; }
__device__ __forceinline__ void storeC(short* p, float v) { *p = f2bf(v); }

// ------------------------------------------- fp32->bf16 (first scaleN scaled)
__global__ void cvt_bf16(const float* __restrict__ in, short* __restrict__ out,
                         long n, float scale, long scaleN) {
  long i = ((long)blockIdx.x * 256 + threadIdx.x) * 8;
  if (i >= n) return;
  float s = (i < scaleN) ? scale : 1.0f;   // regions are 8-aligned
  f32x4 a = *(const f32x4*)(in + i);
  f32x4 b = *(const f32x4*)(in + i + 4);
  short8 o;
  o[0] = f2bf(a[0] * s); o[1] = f2bf(a[1] * s); o[2] = f2bf(a[2] * s); o[3] = f2bf(a[3] * s);
  o[4] = f2bf(b[0] * s); o[5] = f2bf(b[1] * s); o[6] = f2bf(b[2] * s); o[7] = f2bf(b[3] * s);
  *(short8*)(out + i) = o;
}

// ------------------------------------------------------- C = A * B^T (gemm_bt)
// 128x128 tile, BK=64, 4 waves. Staging source pre-swizzled sc = c ^ (row&7);
// reads un-swizzle with off = (kk*32 + g*8) ^ ((row&7)*8).
template <typename CT>
__global__ __launch_bounds__(256, 4)
void gemm_bt(const short* __restrict__ A, const short* __restrict__ B,
             CT* __restrict__ C, int M, int N, int K) {
  __shared__ short As[128 * 64];
  __shared__ short Bs[128 * 64];
  const int tid = threadIdx.x;
  const int wave = tid >> 6, lane = tid & 63;
  const int g = lane >> 4, fr = lane & 15;
  const int wr = (wave >> 1) * 64, wc = (wave & 1) * 64;
  const int bm = blockIdx.y * 128, bn = blockIdx.x * 128;

  f32x4 acc[4][4] = {};

  for (int k0 = 0; k0 < K; k0 += 64) {
    __syncthreads();
#pragma unroll
    for (int i = 0; i < 4; ++i) {
      int Ci = i * 256 + tid;
      int row = Ci >> 3, c = Ci & 7;
      int sc = c ^ (row & 7);
      GLOAD_LDS16(A + (size_t)(bm + row) * K + k0 + sc * 8, As + Ci * 8);
      GLOAD_LDS16(B + (size_t)(bn + row) * K + k0 + sc * 8, Bs + Ci * 8);
    }
    __syncthreads();

#pragma unroll
    for (int kk = 0; kk < 2; ++kk) {
      short8 af[4], bfr[4];
#pragma unroll
      for (int m = 0; m < 4; ++m) {
        int row = wr + m * 16 + fr;
        int off = (kk * 32 + g * 8) ^ ((row & 7) * 8);
        af[m] = *(const short8*)(As + row * 64 + off);
      }
#pragma unroll
      for (int n = 0; n < 4; ++n) {
        int row = wc + n * 16 + fr;
        int off = (kk * 32 + g * 8) ^ ((row & 7) * 8);
        bfr[n] = *(const short8*)(Bs + row * 64 + off);
      }
#pragma unroll
      for (int m = 0; m < 4; ++m)
#pragma unroll
        for (int n = 0; n < 4; ++n)
          acc[m][n] = MFMA16(af[m], bfr[n], acc[m][n]);
    }
  }

#pragma unroll
  for (int m = 0; m < 4; ++m) {
#pragma unroll
    for (int r = 0; r < 4; ++r) {
      size_t row = (size_t)(bm + wr + m * 16 + g * 4 + r);
      CT* cp = C + row * N + bn + wc + fr;
#pragma unroll
      for (int n = 0; n < 4; ++n)
        storeC(cp + n * 16, acc[m][n][r]);
    }
  }
}

// ----------------------------------------------------- V transpose + swizzle
__global__ __launch_bounds__(256, 4)
void vtrans(const short* __restrict__ qkv, short* __restrict__ vtg) {
  __shared__ short L[128 * 64];
  const int tid = threadIdx.x;
  const int tb = blockIdx.x * 64;   // token base
  const int h = blockIdx.y;
#pragma unroll
  for (int i = 0; i < 4; ++i) {
    int Ci = i * 256 + tid, tok = Ci >> 4, c = Ci & 15, f0 = c * 8;
    short8 v = *(const short8*)(qkv + (size_t)(tb + tok) * 6144 + 4096 + h * 128 + f0);
#pragma unroll
    for (int j = 0; j < 8; ++j) {
      int f = f0 + j;
      L[f * 64 + (tok ^ ((((f & 7) ^ ((f >> 3) & 7)) << 3)))] = v[j];
    }
  }
  __syncthreads();
  const int f = tid >> 1, half = (tid & 1) * 32;
  const int s_in = ((f & 7) ^ ((f >> 3) & 7)) << 3;
  const int s_out = (f & 7) << 3;
#pragma unroll
  for (int j2 = 0; j2 < 4; ++j2) {
    int t0 = half + j2 * 8;
    short8 v = *(const short8*)(&L[f * 64 + (t0 ^ s_in)]);
    *(short8*)(vtg + (size_t)(h * 128 + f) * 4096 + tb + (t0 ^ s_out)) = v;
  }
}

// -------------------------------------------------------------- attention
// Grid 512 = 32 q-blocks (QBLK=128) x 16 heads. 4 waves x 32 q-rows.
// LDS 64 KB (Ks dbuf 32 + Vt single 16 + Ps 16) -> 2 blocks/CU.
// Balance: dispatch-slot 0 gets long blocks (x=31-k), slot 1 short (x=k):
// co-resident pair sums to 66 tiles. 2 heads per XCD (L2 ownership).
// Two barriers/tile: mid (drains V(t),K(t+1) staging) + end (Vt WAR guard).
__global__ __launch_bounds__(256, 2)
void attn_fwd(const short* __restrict__ qkv, const short* __restrict__ vtg,
              short* __restrict__ y) {
  __shared__ short Ks[2][64 * 128];   // 32 KB: K dbuf, chunk-swizzled (c^=key&7)
  __shared__ short Vt[128 * 64];      // 16 KB: V^T [feat][key^((feat&7)<<3)]
  __shared__ short Ps[4][32 * 64];    // 16 KB: per-wave P [q][key^PSWZ(q)]
  const int tid = threadIdx.x;
  const int wave = tid >> 6, lane = tid & 63;
  const int g = lane >> 4, fr = lane & 15;

  const int wgid = blockIdx.x;
  const int xcd = wgid & 7, mid = (wgid >> 3) & 31, slot = wgid >> 8;
  const int h = (xcd << 1) | (mid & 1);       // 2 heads per XCD
  const int xq = mid >> 1;                     // 0..15
  const int x = slot ? xq : 31 - xq;           // long blocks in slot 0
  const int qw = x * 128 + wave * 32;
  const int ntiles = 2 * x + 2;

  short* Pw = Ps[wave];

  short8 onesf;
#pragma unroll
  for (int j = 0; j < 8; ++j) onesf[j] = (short)0x3F80;  // bf16 1.0

  short8 qf[2][4];
#pragma unroll
  for (int mi = 0; mi < 2; ++mi) {
    const short* Qp = qkv + (size_t)(qw + mi * 16 + fr) * 6144 + h * 128;
#pragma unroll
    for (int kk = 0; kk < 4; ++kk)
      qf[mi][kk] = *(const short8*)(Qp + kk * 32 + g * 8);
  }
  f32x4 oacc[2][8] = {};
  f32x4 lacc[2] = {};

  // prologue: stage K0 -> Ks[0], V0 -> Vt
#pragma unroll
  for (int i = 0; i < 4; ++i) {
    int Ci = i * 256 + tid, key = Ci >> 4, c = Ci & 15, sc = c ^ (key & 7);
    GLOAD_LDS16(qkv + (size_t)key * 6144 + 2048 + h * 128 + sc * 8, &Ks[0][Ci * 8]);
  }
#pragma unroll
  for (int i = 0; i < 4; ++i) {
    int Ci = i * 256 + tid, feat = Ci >> 3, ko = (Ci & 7) * 8;
    GLOAD_LDS16(vtg + (size_t)(h * 128 + feat) * 4096 + ko, &Vt[Ci * 8]);
  }
  __syncthreads();

#pragma unroll 1
  for (int t = 0; t < ntiles; ++t) {
    const int kv0 = t * 64;
    const int cur = t & 1;

    // A: stage V(t) (t>0; WAR-safe after previous end barrier) and K(t+1)
    if (t > 0) {
#pragma unroll
      for (int i = 0; i < 4; ++i) {
        int Ci = i * 256 + tid, feat = Ci >> 3, ko = (Ci & 7) * 8;
        GLOAD_LDS16(vtg + (size_t)(h * 128 + feat) * 4096 + kv0 + ko, &Vt[Ci * 8]);
      }
    }
    if (t + 1 < ntiles) {
#pragma unroll
      for (int i = 0; i < 4; ++i) {
        int Ci = i * 256 + tid, key = Ci >> 4, c = Ci & 15, sc = c ^ (key & 7);
        GLOAD_LDS16(qkv + (size_t)(kv0 + 64 + key) * 6144 + 2048 + h * 128 + sc * 8,
                    &Ks[cur ^ 1][Ci * 8]);
      }
    }

    const bool active = (kv0 <= qw + 31);  // wave-uniform: any unmasked key?

    if (active) {
      // B: S = Q K^T; each kfrag feeds both m-frags
      f32x4 s[2][4] = {};
      __builtin_amdgcn_s_setprio(1);
#pragma unroll
      for (int nf = 0; nf < 4; ++nf) {
        const int key = nf * 16 + fr;
#pragma unroll
        for (int kk = 0; kk < 4; ++kk) {
          int off = (kk * 32 + g * 8) ^ ((key & 7) * 8);
          short8 kfrag = *(const short8*)(&Ks[cur][key * 128 + off]);
          s[0][nf] = MFMA16(qf[0][kk], kfrag, s[0][nf]);
          s[1][nf] = MFMA16(qf[1][kk], kfrag, s[1][nf]);
        }
      }
      __builtin_amdgcn_s_setprio(0);

      // C: P = exp2(S); causal mask only in the diagonal region (last 2 tiles)
      if (t >= ntiles - 2) {
#pragma unroll
        for (int mi = 0; mi < 2; ++mi)
#pragma unroll
          for (int nf = 0; nf < 4; ++nf) {
            const int keyg = kv0 + nf * 16 + fr;
#pragma unroll
            for (int r = 0; r < 4; ++r) {
              const int q2 = mi * 16 + g * 4 + r;
              float p = (keyg <= qw + q2) ? __builtin_amdgcn_exp2f(s[mi][nf][r]) : 0.f;
              Pw[q2 * 64 + ((nf * 16 + fr) ^ PSWZ(q2))] = f2bf(p);
            }
          }
      } else {
#pragma unroll
        for (int mi = 0; mi < 2; ++mi)
#pragma unroll
          for (int nf = 0; nf < 4; ++nf)
#pragma unroll
            for (int r = 0; r < 4; ++r) {
              const int q2 = mi * 16 + g * 4 + r;
              Pw[q2 * 64 + ((nf * 16 + fr) ^ PSWZ(q2))] =
                  f2bf(__builtin_amdgcn_exp2f(s[mi][nf][r]));
            }
      }
    }

    // mid barrier: V(t), K(t+1) staging landed; all waves aligned
    __syncthreads();

    if (active) {
      // D: O += P V ; l += P 1  (vf feeds both m-frags)
      __builtin_amdgcn_s_setprio(1);
#pragma unroll
      for (int kk = 0; kk < 2; ++kk) {
        const int rb = kk * 32 + g * 8;
        short8 pf0 = *(const short8*)(&Pw[fr * 64 + (rb ^ PSWZ(fr))]);
        short8 pf1 = *(const short8*)(&Pw[(16 + fr) * 64 + (rb ^ PSWZ(16 + fr))]);
        lacc[0] = MFMA16(pf0, onesf, lacc[0]);
        lacc[1] = MFMA16(pf1, onesf, lacc[1]);
#pragma unroll
        for (int nf = 0; nf < 8; ++nf) {
          int f = nf * 16 + fr;
          short8 vf = *(const short8*)(&Vt[f * 64 + (rb ^ ((f & 7) * 8))]);
          oacc[0][nf] = MFMA16(pf0, vf, oacc[0][nf]);
          oacc[1][nf] = MFMA16(pf1, vf, oacc[1][nf]);
        }
      }
      __builtin_amdgcn_s_setprio(0);
    }

    // end barrier: Vt reads complete before next tile's V staging (WAR)
    __syncthreads();
  }

  // epilogue: y = O / l
#pragma unroll
  for (int mi = 0; mi < 2; ++mi)
#pragma unroll
    for (int r = 0; r < 4; ++r) {
      float inv = 1.0f / lacc[mi][r];
      size_t row = (size_t)(qw + mi * 16 + g * 4 + r);
#pragma unroll
      for (int nf = 0; nf < 8; ++nf)
        y[row * 2048 + h * 128 + nf * 16 + fr] = f2bf(oacc[mi][nf][r] * inv);
    }
}

// ---------------------------------------------------------------------------
extern "C" void kernel_launch(void* const* d_in, const int* in_sizes, int n_in,
                              void* d_out, int out_size, void* d_ws, size_t ws_size,
                              hipStream_t stream) {
  const float* x    = (const float*)d_in[0];   // [4096,2048]
  const float* Win  = (const float*)d_in[1];   // [6144,2048]
  const float* Wout = (const float*)d_in[2];   // [2048,2048]
  float* out = (float*)d_out;                  // [4096,2048] fp32

  char* ws = (char*)d_ws;
  // lifetimes: xb,Winb dead after GEMM1 -> yb aliases xb, vtg aliases Winb
  short* xb    = (short*)(ws);                 // 16 MB : x bf16       [0,16M)
  short* yb    = (short*)(ws);                 // 16 MB : y bf16       [0,16M)
  short* Winb  = (short*)(ws + 16777216);      // 24 MB : W_in bf16    [16M,40M)
  short* vtg   = (short*)(ws + 16777216);      // 16 MB : V^T swz      [16M,32M)
  short* Woutb = (short*)(ws + 41943040);      //  8 MB : W_out bf16   [40M,48M)
  short* qkv   = (short*)(ws + 50331648);      // 48 MB : qkv bf16     [48M,96M)

  // Q-scale folded into W_in rows [0,2048) = first 2048*2048 elements
  const float qscale = 0.08838834764831845f * 1.4426950408889634f;

  cvt_bf16<<<4096, 256, 0, stream>>>(x, xb, 8388608L, 1.0f, 0L);
  cvt_bf16<<<6144, 256, 0, stream>>>(Win, Winb, 12582912L, qscale, 4194304L);
  cvt_bf16<<<2048, 256, 0, stream>>>(Wout, Woutb, 4194304L, 1.0f, 0L);

  gemm_bt<short><<<dim3(48, 32), 256, 0, stream>>>(xb, Winb, qkv, 4096, 6144, 2048);

  vtrans<<<dim3(64, 16), 256, 0, stream>>>(qkv, vtg);

  attn_fwd<<<512, 256, 0, stream>>>(qkv, vtg, yb);

  gemm_bt<float><<<dim3(16, 32), 256, 0, stream>>>(yb, Woutb, out, 4096, 2048, 2048);
}